// Round 1
// baseline (140.286 us; speedup 1.0000x reference)
//
#include <hip/hip_runtime.h>
#include <math.h>

// TeacherMLP: h_next[b][o] = sum_i g(h[b][i] * We[o][i]) + bias[o]
//   We = atom(W, f_idx) elementwise, atoms = [id, sin, tanh, square]
//   g = tanh on layers 0,1; identity on layer 2.
// Hidden layers are NOT matmuls (tanh inside the sum) -> VALU/trans-bound.
//
// Kernel 1: build TRANSPOSED effective weights WeT[i][o] in d_ws (coalesced
//           weight loads in the main loop).
// Kernel 2: fully fused 3-layer forward; 4 batch rows per block, activations
//           ping-pong in LDS, pre-scaled by 2*log2(e) so tanh = 1 - 2*rcp(exp2(hs*w)+1)
//           and sum_tanh = 256 - 2*sum(rcp terms).

#define RB 4  // batch rows per block

__device__ __forceinline__ float fast_rcp(float x)  { return __builtin_amdgcn_rcpf(x); }
__device__ __forceinline__ float fast_exp2(float x) { return __builtin_amdgcn_exp2f(x); }

__global__ void weff_kernel(const float* __restrict__ W0, const int* __restrict__ I0,
                            const float* __restrict__ W1, const int* __restrict__ I1,
                            const float* __restrict__ W2, const int* __restrict__ I2,
                            float* __restrict__ ws) {
    int tid = blockIdx.x * blockDim.x + threadIdx.x;   // 0 .. 163839
    const float* W; const int* I; float* out; int outd; int e;
    if (tid < 65536)        { W = W0; I = I0; out = ws;          outd = 256; e = tid; }
    else if (tid < 131072)  { W = W1; I = I1; out = ws + 65536;  outd = 256; e = tid - 65536; }
    else if (tid < 163840)  { W = W2; I = I2; out = ws + 131072; outd = 128; e = tid - 131072; }
    else return;
    int o = e >> 8;       // out index (in-dim is always 256)
    int i = e & 255;      // in index
    float w = W[e];       // coalesced read (e = o*256 + i)
    int idx = I[e];
    float v = w;                       // atom 0: identity
    if (idx == 1) v = sinf(w);         // atom 1: sin (accurate; tiny count)
    else if (idx == 2) v = tanhf(w);   // atom 2: tanh
    else if (idx == 3) v = w * w;      // atom 3: square
    out[i * outd + o] = v;             // transposed store
}

__global__ __launch_bounds__(256) void mlp_kernel(
    const float* __restrict__ x,  const float* __restrict__ b0,
    const float* __restrict__ b1, const float* __restrict__ b2,
    const float* __restrict__ ws, float* __restrict__ out) {
    const float* We0 = ws;            // [i=256][o=256]
    const float* We1 = ws + 65536;    // [i=256][o=256]
    const float* We2 = ws + 131072;   // [i=256][o=128]

    __shared__ __align__(16) float hA[RB][256];
    __shared__ __align__(16) float hB[RB][256];

    const int t = threadIdx.x;          // output-neuron index for layers 0,1
    const int row0 = blockIdx.x * RB;   // first batch row of this block
    const float SC  = 2.885390081777927f;   // 2*log2(e): exp2(SC*z) = e^{2z}
    const float INV = 1.0f / 2.885390081777927f;

    // stage input rows (pre-scaled)
#pragma unroll
    for (int k = 0; k < RB; k++)
        hA[k][t] = x[(row0 + k) * 256 + t] * SC;
    __syncthreads();

    // ---------------- layer 0: hA -> hB (tanh) ----------------
    {
        const float bias = b0[t];
        float acc[RB];
#pragma unroll
        for (int r = 0; r < RB; r++) acc[r] = 0.f;
        for (int i = 0; i < 256; i += 4) {
            float w0 = We0[(i + 0) * 256 + t];
            float w1 = We0[(i + 1) * 256 + t];
            float w2 = We0[(i + 2) * 256 + t];
            float w3 = We0[(i + 3) * 256 + t];
#pragma unroll
            for (int r = 0; r < RB; r++) {
                float4 h4 = *(const float4*)&hA[r][i];   // LDS broadcast
                acc[r] += fast_rcp(fast_exp2(h4.x * w0) + 1.f);
                acc[r] += fast_rcp(fast_exp2(h4.y * w1) + 1.f);
                acc[r] += fast_rcp(fast_exp2(h4.z * w2) + 1.f);
                acc[r] += fast_rcp(fast_exp2(h4.w * w3) + 1.f);
            }
        }
#pragma unroll
        for (int r = 0; r < RB; r++)
            hB[r][t] = (256.0f - 2.0f * acc[r] + bias) * SC;
        __syncthreads();
    }

    // ---------------- layer 1: hB -> hA (tanh) ----------------
    {
        const float bias = b1[t];
        float acc[RB];
#pragma unroll
        for (int r = 0; r < RB; r++) acc[r] = 0.f;
        for (int i = 0; i < 256; i += 4) {
            float w0 = We1[(i + 0) * 256 + t];
            float w1 = We1[(i + 1) * 256 + t];
            float w2 = We1[(i + 2) * 256 + t];
            float w3 = We1[(i + 3) * 256 + t];
#pragma unroll
            for (int r = 0; r < RB; r++) {
                float4 h4 = *(const float4*)&hB[r][i];
                acc[r] += fast_rcp(fast_exp2(h4.x * w0) + 1.f);
                acc[r] += fast_rcp(fast_exp2(h4.y * w1) + 1.f);
                acc[r] += fast_rcp(fast_exp2(h4.z * w2) + 1.f);
                acc[r] += fast_rcp(fast_exp2(h4.w * w3) + 1.f);
            }
        }
#pragma unroll
        for (int r = 0; r < RB; r++)
            hA[r][t] = (256.0f - 2.0f * acc[r] + bias) * SC;
        __syncthreads();
    }

    // ---------------- layer 2: hA -> out (identity, a real matmul) --------
    {
        const int o  = t & 127;     // output neuron
        const int rg = t >> 7;      // row group: 0 -> rows 0,1 ; 1 -> rows 2,3
        const float bias = b2[o];
        float acc0 = 0.f, acc1 = 0.f;
        for (int i = 0; i < 256; i += 4) {
            float w0 = We2[(i + 0) * 128 + o];
            float w1 = We2[(i + 1) * 128 + o];
            float w2 = We2[(i + 2) * 128 + o];
            float w3 = We2[(i + 3) * 128 + o];
            {
                float4 h4 = *(const float4*)&hA[rg * 2 + 0][i];
                acc0 += h4.x * w0 + h4.y * w1 + h4.z * w2 + h4.w * w3;
            }
            {
                float4 h4 = *(const float4*)&hA[rg * 2 + 1][i];
                acc1 += h4.x * w0 + h4.y * w1 + h4.z * w2 + h4.w * w3;
            }
        }
        // activations were pre-scaled by SC; fold 1/SC into the epilogue
        out[(row0 + rg * 2 + 0) * 128 + o] = acc0 * INV + bias;
        out[(row0 + rg * 2 + 1) * 128 + o] = acc1 * INV + bias;
    }
}

extern "C" void kernel_launch(void* const* d_in, const int* in_sizes, int n_in,
                              void* d_out, int out_size, void* d_ws, size_t ws_size,
                              hipStream_t stream) {
    const float* x  = (const float*)d_in[0];
    const float* W0 = (const float*)d_in[1];
    const float* b0 = (const float*)d_in[2];
    const int*   I0 = (const int*)  d_in[3];
    const float* W1 = (const float*)d_in[4];
    const float* b1 = (const float*)d_in[5];
    const int*   I1 = (const int*)  d_in[6];
    const float* W2 = (const float*)d_in[7];
    const float* b2 = (const float*)d_in[8];
    const int*   I2 = (const int*)  d_in[9];
    float* ws  = (float*)d_ws;    // needs 163840 floats = 655360 B
    float* out = (float*)d_out;

    weff_kernel<<<640, 256, 0, stream>>>(W0, I0, W1, I1, W2, I2, ws);
    mlp_kernel<<<2048 / RB, 256, 0, stream>>>(x, b0, b1, b2, ws, out);
}

// Round 2
// 130.003 us; speedup vs baseline: 1.0791x; 1.0791x over previous
//
#include <hip/hip_runtime.h>
#include <math.h>

// TeacherMLP fused forward.
// R2 changes vs R1:
//  - RB 4->2, grid 512->1024 blocks: 4 blocks/CU -> 16 waves/CU (was 8).
//    R1 showed OccupancyPercent=20, VALUBusy=63 -> latency-bound on the
//    mul->exp2->add->rcp->add chain. More waves to hide it.
//  - weight layout packed as [i/4][o][4]: each thread loads its 4 K-values
//    as one float4 (coalesced 1KB/wave), 1/4 the weight-load instructions.
//  - weff_kernel: libm sinf/tanhf -> hw v_sin + exp2-based tanh, branchless
//    (R1 total was 140us vs 71.6 for mlp -> weff suspected ~68us).

#define RB 2  // batch rows per block

__device__ __forceinline__ float fast_rcp(float x)  { return __builtin_amdgcn_rcpf(x); }
__device__ __forceinline__ float fast_exp2(float x) { return __builtin_amdgcn_exp2f(x); }

#define SC  2.885390081777927f      /* 2*log2(e): exp2(SC*z) = e^{2z} */
#define INV (1.0f / 2.885390081777927f)
#define INV2PI 0.15915494309189535f /* 1/(2pi) for v_sin (revolutions) */

__global__ void weff_kernel(const float* __restrict__ W0, const int* __restrict__ I0,
                            const float* __restrict__ W1, const int* __restrict__ I1,
                            const float* __restrict__ W2, const int* __restrict__ I2,
                            float* __restrict__ ws) {
    int tid = blockIdx.x * blockDim.x + threadIdx.x;   // 0 .. 163839
    const float* W; const int* I; float* out; int outd; int e;
    if (tid < 65536)        { W = W0; I = I0; out = ws;          outd = 256; e = tid; }
    else if (tid < 131072)  { W = W1; I = I1; out = ws + 65536;  outd = 256; e = tid - 65536; }
    else if (tid < 163840)  { W = W2; I = I2; out = ws + 131072; outd = 128; e = tid - 131072; }
    else return;
    int o = e >> 8;       // out index (in-dim is always 256)
    int i = e & 255;      // in index
    float w = W[e];       // coalesced (e = o*256 + i)
    int idx = I[e];
    // branchless atoms: [id, sin, tanh, square]
    float sn = __builtin_amdgcn_sinf(w * INV2PI);               // hw sin, revolutions
    float th = 1.0f - 2.0f * fast_rcp(fast_exp2(w * SC) + 1.0f);
    float sq = w * w;
    float v = (idx == 1) ? sn : (idx == 2) ? th : (idx == 3) ? sq : w;
    // packed store: [i/4][o][i%4]  -> main loop reads float4 of 4 K-values
    out[(i >> 2) * (outd * 4) + o * 4 + (i & 3)] = v;
}

__global__ __launch_bounds__(256) void mlp_kernel(
    const float* __restrict__ x,  const float* __restrict__ b0,
    const float* __restrict__ b1, const float* __restrict__ b2,
    const float* __restrict__ ws, float* __restrict__ out) {
    // packed float4 views: index = (i>>2)*outd + o
    const float4* We0 = (const float4*)ws;             // [64][256]
    const float4* We1 = (const float4*)(ws + 65536);   // [64][256]
    const float4* We2 = (const float4*)(ws + 131072);  // [64][128]

    __shared__ __align__(16) float hA[RB][256];
    __shared__ __align__(16) float hB[RB][256];

    const int t = threadIdx.x;          // output-neuron index for layers 0,1
    const int row0 = blockIdx.x * RB;

    // stage input rows (pre-scaled by SC)
#pragma unroll
    for (int k = 0; k < RB; k++)
        hA[k][t] = x[(row0 + k) * 256 + t] * SC;
    __syncthreads();

    // ---------------- layer 0: hA -> hB (tanh) ----------------
    {
        const float bias = b0[t];
        float acc0 = 0.f, acc1 = 0.f;
#pragma unroll 4
        for (int ic = 0; ic < 64; ic++) {
            float4 w  = We0[ic * 256 + t];               // 4 K-values, one load
            float4 h0 = *(const float4*)&hA[0][ic * 4];  // LDS broadcast
            float4 h1 = *(const float4*)&hA[1][ic * 4];
            acc0 += fast_rcp(fast_exp2(h0.x * w.x) + 1.f);
            acc0 += fast_rcp(fast_exp2(h0.y * w.y) + 1.f);
            acc0 += fast_rcp(fast_exp2(h0.z * w.z) + 1.f);
            acc0 += fast_rcp(fast_exp2(h0.w * w.w) + 1.f);
            acc1 += fast_rcp(fast_exp2(h1.x * w.x) + 1.f);
            acc1 += fast_rcp(fast_exp2(h1.y * w.y) + 1.f);
            acc1 += fast_rcp(fast_exp2(h1.z * w.z) + 1.f);
            acc1 += fast_rcp(fast_exp2(h1.w * w.w) + 1.f);
        }
        hB[0][t] = (256.0f - 2.0f * acc0 + bias) * SC;
        hB[1][t] = (256.0f - 2.0f * acc1 + bias) * SC;
        __syncthreads();
    }

    // ---------------- layer 1: hB -> hA (tanh) ----------------
    {
        const float bias = b1[t];
        float acc0 = 0.f, acc1 = 0.f;
#pragma unroll 4
        for (int ic = 0; ic < 64; ic++) {
            float4 w  = We1[ic * 256 + t];
            float4 h0 = *(const float4*)&hB[0][ic * 4];
            float4 h1 = *(const float4*)&hB[1][ic * 4];
            acc0 += fast_rcp(fast_exp2(h0.x * w.x) + 1.f);
            acc0 += fast_rcp(fast_exp2(h0.y * w.y) + 1.f);
            acc0 += fast_rcp(fast_exp2(h0.z * w.z) + 1.f);
            acc0 += fast_rcp(fast_exp2(h0.w * w.w) + 1.f);
            acc1 += fast_rcp(fast_exp2(h1.x * w.x) + 1.f);
            acc1 += fast_rcp(fast_exp2(h1.y * w.y) + 1.f);
            acc1 += fast_rcp(fast_exp2(h1.z * w.z) + 1.f);
            acc1 += fast_rcp(fast_exp2(h1.w * w.w) + 1.f);
        }
        hA[0][t] = (256.0f - 2.0f * acc0 + bias) * SC;
        hA[1][t] = (256.0f - 2.0f * acc1 + bias) * SC;
        __syncthreads();
    }

    // ---------------- layer 2: hA -> out (identity matmul) ----------------
    {
        const int o = t & 127;      // output neuron
        const int r = t >> 7;       // which of the 2 rows
        float acc = 0.f;
#pragma unroll 4
        for (int ic = 0; ic < 64; ic++) {
            float4 w = We2[ic * 128 + o];
            float4 h = *(const float4*)&hA[r][ic * 4];
            acc += h.x * w.x + h.y * w.y + h.z * w.z + h.w * w.w;
        }
        out[(row0 + r) * 128 + o] = acc * INV + b2[o];  // undo SC pre-scale
    }
}

extern "C" void kernel_launch(void* const* d_in, const int* in_sizes, int n_in,
                              void* d_out, int out_size, void* d_ws, size_t ws_size,
                              hipStream_t stream) {
    const float* x  = (const float*)d_in[0];
    const float* W0 = (const float*)d_in[1];
    const float* b0 = (const float*)d_in[2];
    const int*   I0 = (const int*)  d_in[3];
    const float* W1 = (const float*)d_in[4];
    const float* b1 = (const float*)d_in[5];
    const int*   I1 = (const int*)  d_in[6];
    const float* W2 = (const float*)d_in[7];
    const float* b2 = (const float*)d_in[8];
    const int*   I2 = (const int*)  d_in[9];
    float* ws  = (float*)d_ws;    // 163840 floats = 655360 B
    float* out = (float*)d_out;

    weff_kernel<<<640, 256, 0, stream>>>(W0, I0, W1, I1, W2, I2, ws);
    mlp_kernel<<<2048 / RB, 256, 0, stream>>>(x, b0, b1, b2, ws, out);
}